// Round 2
// baseline (39034.665 us; speedup 1.0000x reference)
//
#include <hip/hip_runtime.h>
#include <math.h>

// Problem constants (fixed by the reference)
#define DM 1024
#define SEQ 2048
#define BATCH 2
#define NHEAD 16
#define HDIM 64
#define NLAYER 8
#define FFDIM 4096
#define MROWS (BATCH*SEQ)    // 4096
#define QSTR 3072            // fused qkv row stride

typedef __attribute__((ext_vector_type(8))) unsigned short short8;
typedef __attribute__((ext_vector_type(8))) __bf16 bf16x8;
typedef __attribute__((ext_vector_type(4))) float f32x4;

__device__ __forceinline__ float softplus_f(float x){
    return fmaxf(x, 0.0f) + log1pf(__expf(-fabsf(x)));
}

// fp32 -> bf16 round-to-nearest-even (finite inputs)
__device__ __forceinline__ unsigned short f2bf(float f){
    unsigned u = __builtin_bit_cast(unsigned, f);
    u += 0x7fffu + ((u >> 16) & 1u);
    return (unsigned short)(u >> 16);
}

// async global->LDS, 16B per lane; LDS dest = wave-uniform base + lane*16
__device__ __forceinline__ void gload_lds16(const void* g, void* l){
    __builtin_amdgcn_global_load_lds(
        (const __attribute__((address_space(1))) unsigned int*)g,
        (__attribute__((address_space(3))) unsigned int*)l, 16, 0, 0);
}

// ---------------------------------------------------------------------------
// Transpose-cast: src fp32 [K,N] row-major -> dst bf16 [N,K] row-major.
// grid (N/32, K/32), block 256 (32x8).
__global__ __launch_bounds__(256) void tcast_kernel(
    const float* __restrict__ src, unsigned short* __restrict__ dst, int K, int N)
{
    __shared__ float tile[32][33];
    const int bn = blockIdx.x * 32, bk = blockIdx.y * 32;
    const int tx = threadIdx.x & 31, ty = threadIdx.x >> 5;
    #pragma unroll
    for (int i = 0; i < 32; i += 8)
        tile[ty + i][tx] = src[(size_t)(bk + ty + i) * N + bn + tx];
    __syncthreads();
    #pragma unroll
    for (int i = 0; i < 32; i += 8)
        dst[(size_t)(bn + ty + i) * K + bk + tx] = f2bf(tile[tx][ty + i]);
}

// concat [bq | bkv] per layer into [NLAYER][3072] fp32
__global__ __launch_bounds__(256) void bias_concat_kernel(
    const float* __restrict__ bq, const float* __restrict__ bkv, float* __restrict__ dst)
{
    const int i = blockIdx.x * 256 + threadIdx.x;   // < 8*3072
    const int l = i / QSTR, c = i % QSTR;
    dst[i] = (c < DM) ? bq[l * DM + c] : bkv[l * 2 * DM + (c - DM)];
}

// ---------------------------------------------------------------------------
// LayerNorm: one block per row of 1024 floats. eps=1e-3. Output fp32 or bf16.
template<bool OUT_BF16>
__global__ __launch_bounds__(256) void ln_kernel(
    const float* __restrict__ x, const float* __restrict__ gamma,
    const float* __restrict__ beta, void* __restrict__ outv)
{
    const int row = blockIdx.x;
    const int t = threadIdx.x;
    const float4 v = ((const float4*)(x + (size_t)row * DM))[t];
    float s  = v.x + v.y + v.z + v.w;
    float s2 = v.x*v.x + v.y*v.y + v.z*v.z + v.w*v.w;
    #pragma unroll
    for (int off = 32; off > 0; off >>= 1){
        s  += __shfl_down(s,  off);
        s2 += __shfl_down(s2, off);
    }
    __shared__ float red[8];
    const int wid = t >> 6;
    if ((t & 63) == 0){ red[wid] = s; red[4 + wid] = s2; }
    __syncthreads();
    if (t == 0){
        red[0] = red[0] + red[1] + red[2] + red[3];
        red[4] = red[4] + red[5] + red[6] + red[7];
    }
    __syncthreads();
    const float mean = red[0] * (1.0f / DM);
    const float var  = red[4] * (1.0f / DM) - mean * mean;
    const float rstd = rsqrtf(var + 1e-3f);
    const float4 g  = ((const float4*)gamma)[t];
    const float4 bt = ((const float4*)beta)[t];
    float ox = (v.x - mean) * rstd * g.x + bt.x;
    float oy = (v.y - mean) * rstd * g.y + bt.y;
    float oz = (v.z - mean) * rstd * g.z + bt.z;
    float ow = (v.w - mean) * rstd * g.w + bt.w;
    if (OUT_BF16){
        ushort4 o = make_ushort4(f2bf(ox), f2bf(oy), f2bf(oz), f2bf(ow));
        *(ushort4*)((unsigned short*)outv + (size_t)row * DM + t*4) = o;
    } else {
        ((float4*)((float*)outv + (size_t)row * DM))[t] = make_float4(ox, oy, oz, ow);
    }
}

// ---------------------------------------------------------------------------
// bf16 MFMA GEMM (m97 structure): C[M,N] = A[M,K] @ Bt[N,K]^T + bias.
// A, Bt bf16 row-major; 128x128 tile, BK=32, 256 threads = 4 waves in 2x2;
// each wave: 4x4 grid of 16x16x32 MFMA tiles. global_load_lds width-16 staging.
template<bool SOFTPLUS, bool RESIDUAL, bool OUT_BF16>
__global__ __launch_bounds__(256) void gemm_bf16_kernel(
    const unsigned short* __restrict__ A, const unsigned short* __restrict__ Bt,
    const float* __restrict__ bias, const float* __restrict__ resid,
    void* __restrict__ Cv, int N, int K)
{
    __shared__ __align__(16) unsigned short As[128 * 32];
    __shared__ __align__(16) unsigned short Bs[128 * 32];
    const int t = threadIdx.x;
    const int lane = t & 63, w = t >> 6;
    const int bm = blockIdx.y * 128, bn = blockIdx.x * 128;

    // staging: wave w covers tile rows [w*32, w*32+32) in two 16-row calls.
    // lane -> (row = lane>>2, col8 = (lane&3)*8) == LDS base + lane*16B.
    const int srow = lane >> 2;
    const int scol = (lane & 3) * 8;
    const unsigned short* a_g0 = A  + (size_t)(bm + w*32 + srow) * K + scol;
    const unsigned short* a_g1 = a_g0 + (size_t)16 * K;
    const unsigned short* b_g0 = Bt + (size_t)(bn + w*32 + srow) * K + scol;
    const unsigned short* b_g1 = b_g0 + (size_t)16 * K;
    unsigned short* a_l0 = &As[(w*32     ) * 32];
    unsigned short* a_l1 = &As[(w*32 + 16) * 32];
    unsigned short* b_l0 = &Bs[(w*32     ) * 32];
    unsigned short* b_l1 = &Bs[(w*32 + 16) * 32];

    const int wr = (w >> 1) * 64;      // wave's row block in tile
    const int wc = (w & 1) * 64;       // wave's col block in tile
    const int fm = lane & 15;          // fragment m/n index
    const int fq = (lane >> 4) * 8;    // fragment k offset

    f32x4 acc[4][4] = {};

    for (int k0 = 0; k0 < K; k0 += 32){
        __syncthreads();
        gload_lds16(a_g0 + k0, a_l0);
        gload_lds16(a_g1 + k0, a_l1);
        gload_lds16(b_g0 + k0, b_l0);
        gload_lds16(b_g1 + k0, b_l1);
        __syncthreads();   // compiler emits vmcnt(0) drain before barrier

        bf16x8 af[4], bfr[4];
        #pragma unroll
        for (int mi = 0; mi < 4; mi++)
            af[mi] = __builtin_bit_cast(bf16x8,
                *(const short8*)&As[(wr + mi*16 + fm) * 32 + fq]);
        #pragma unroll
        for (int ni = 0; ni < 4; ni++)
            bfr[ni] = __builtin_bit_cast(bf16x8,
                *(const short8*)&Bs[(wc + ni*16 + fm) * 32 + fq]);
        #pragma unroll
        for (int mi = 0; mi < 4; mi++)
            #pragma unroll
            for (int ni = 0; ni < 4; ni++)
                acc[mi][ni] = __builtin_amdgcn_mfma_f32_16x16x32_bf16(
                    af[mi], bfr[ni], acc[mi][ni], 0, 0, 0);
    }

    // C/D layout: row = (lane>>4)*4 + reg, col = lane&15  [m89/m91 verified]
    const int crow = (lane >> 4) * 4;
    const int ccol = lane & 15;
    #pragma unroll
    for (int mi = 0; mi < 4; mi++){
        #pragma unroll
        for (int r = 0; r < 4; r++){
            const size_t row = (size_t)bm + wr + mi*16 + crow + r;
            #pragma unroll
            for (int ni = 0; ni < 4; ni++){
                const int col = bn + wc + ni*16 + ccol;
                float v = acc[mi][ni][r] + bias[col];
                if (SOFTPLUS) v = softplus_f(v);
                if (RESIDUAL) v += resid[row * N + col];
                if (OUT_BF16) ((unsigned short*)Cv)[row * N + col] = f2bf(v);
                else          ((float*)Cv)[row * N + col] = v;
            }
        }
    }
}

// ---------------------------------------------------------------------------
// Flash attention (fp32, online softmax), ALiBi + causal.
// qkv: fp32 [B*S, 3072] fused (q|k|v). out: bf16 [B*S, 1024].
// Score cols per thread: tx + 16*j  (row stride 68 words -> 2-way LDS alias,
// free; the old tx*4+j mapping was 8-way conflicted).
__global__ __launch_bounds__(256, 2) void attn_kernel(
    const float* __restrict__ qkv, unsigned short* __restrict__ outg)
{
    __shared__ float Qs[64][68];
    __shared__ float Ks[64][68];
    __shared__ float Vs[64][68];
    __shared__ float Ps[64][68];

    const int b = blockIdx.z, h = blockIdx.y, qt = blockIdx.x;
    const int t  = threadIdx.x;
    const int tx = t & 15, ty = t >> 4;
    const int lr = t >> 2, lc = t & 3;

    const size_t qrow0 = (size_t)(b * SEQ + qt * 64);
    #pragma unroll
    for (int j = 0; j < 4; j++){
        const int d4 = lc + j*4;
        *(float4*)&Qs[lr][d4*4] =
            *(const float4*)(qkv + (qrow0 + lr) * QSTR + h*HDIM + d4*4);
    }

    const float mh = exp2f(-0.5f * (float)(h + 1));
    float m_i[4], l_i[4], accO[4][4];
    #pragma unroll
    for (int i = 0; i < 4; i++){
        m_i[i] = -1e30f; l_i[i] = 0.0f;
        accO[i][0] = accO[i][1] = accO[i][2] = accO[i][3] = 0.0f;
    }

    for (int kt = 0; kt <= qt; kt++){
        __syncthreads();
        const size_t krow0 = (size_t)(b * SEQ + kt * 64);
        #pragma unroll
        for (int j = 0; j < 4; j++){
            const int d4 = lc + j*4;
            *(float4*)&Ks[lr][d4*4] =
                *(const float4*)(qkv + (krow0 + lr) * QSTR + DM + h*HDIM + d4*4);
            *(float4*)&Vs[lr][d4*4] =
                *(const float4*)(qkv + (krow0 + lr) * QSTR + 2*DM + h*HDIM + d4*4);
        }
        __syncthreads();

        // QK^T: rows ty*4+i, cols tx+16j
        float sc[4][4] = {};
        #pragma unroll
        for (int d4 = 0; d4 < 16; d4++){
            float4 qv[4], kk[4];
            #pragma unroll
            for (int i = 0; i < 4; i++) qv[i] = *(const float4*)&Qs[ty*4+i][d4*4];
            #pragma unroll
            for (int j = 0; j < 4; j++) kk[j] = *(const float4*)&Ks[tx + 16*j][d4*4];
            #pragma unroll
            for (int i = 0; i < 4; i++)
                #pragma unroll
                for (int j = 0; j < 4; j++)
                    sc[i][j] += qv[i].x*kk[j].x + qv[i].y*kk[j].y
                              + qv[i].z*kk[j].z + qv[i].w*kk[j].w;
        }

        const int q0 = qt*64 + ty*4, k0 = kt*64 + tx;
        #pragma unroll
        for (int i = 0; i < 4; i++)
            #pragma unroll
            for (int j = 0; j < 4; j++){
                const int qi = q0 + i, kj = k0 + 16*j;
                sc[i][j] = (kj <= qi) ? fmaf(sc[i][j], 0.125f, mh * (float)(kj - qi))
                                      : -1e30f;
            }

        float rmax[4], alpha[4], rsum[4];
        #pragma unroll
        for (int i = 0; i < 4; i++)
            rmax[i] = fmaxf(fmaxf(sc[i][0], sc[i][1]), fmaxf(sc[i][2], sc[i][3]));
        #pragma unroll
        for (int off = 1; off < 16; off <<= 1)
            #pragma unroll
            for (int i = 0; i < 4; i++)
                rmax[i] = fmaxf(rmax[i], __shfl_xor(rmax[i], off));
        #pragma unroll
        for (int i = 0; i < 4; i++){
            const float nm = fmaxf(m_i[i], rmax[i]);
            alpha[i] = __expf(m_i[i] - nm);
            m_i[i] = nm;
        }
        #pragma unroll
        for (int i = 0; i < 4; i++){
            float su = 0.0f;
            #pragma unroll
            for (int j = 0; j < 4; j++){
                const float p = __expf(sc[i][j] - m_i[i]);
                sc[i][j] = p; su += p;
            }
            rsum[i] = su;
        }
        #pragma unroll
        for (int off = 1; off < 16; off <<= 1)
            #pragma unroll
            for (int i = 0; i < 4; i++)
                rsum[i] += __shfl_xor(rsum[i], off);
        #pragma unroll
        for (int i = 0; i < 4; i++) l_i[i] = l_i[i] * alpha[i] + rsum[i];

        #pragma unroll
        for (int i = 0; i < 4; i++)
            #pragma unroll
            for (int j = 0; j < 4; j++)
                Ps[ty*4+i][tx + 16*j] = sc[i][j];
        __syncthreads();

        #pragma unroll
        for (int i = 0; i < 4; i++){
            accO[i][0] *= alpha[i]; accO[i][1] *= alpha[i];
            accO[i][2] *= alpha[i]; accO[i][3] *= alpha[i];
        }
        #pragma unroll
        for (int k4 = 0; k4 < 16; k4++){
            float4 pv[4], vv[4];
            #pragma unroll
            for (int i = 0; i < 4; i++) pv[i] = *(const float4*)&Ps[ty*4+i][k4*4];
            #pragma unroll
            for (int j = 0; j < 4; j++) vv[j] = *(const float4*)&Vs[k4*4+j][tx*4];
            #pragma unroll
            for (int i = 0; i < 4; i++){
                const float4 p = pv[i];
                accO[i][0] += p.x*vv[0].x + p.y*vv[1].x + p.z*vv[2].x + p.w*vv[3].x;
                accO[i][1] += p.x*vv[0].y + p.y*vv[1].y + p.z*vv[2].y + p.w*vv[3].y;
                accO[i][2] += p.x*vv[0].z + p.y*vv[1].z + p.z*vv[2].z + p.w*vv[3].z;
                accO[i][3] += p.x*vv[0].w + p.y*vv[1].w + p.z*vv[2].w + p.w*vv[3].w;
            }
        }
    }

    #pragma unroll
    for (int i = 0; i < 4; i++){
        const float inv = 1.0f / l_i[i];
        ushort4 o = make_ushort4(f2bf(accO[i][0]*inv), f2bf(accO[i][1]*inv),
                                 f2bf(accO[i][2]*inv), f2bf(accO[i][3]*inv));
        *(ushort4*)(outg + (qrow0 + ty*4 + i) * DM + h*HDIM + tx*4) = o;
    }
}

// ---------------------------------------------------------------------------
extern "C" void kernel_launch(void* const* d_in, const int* in_sizes, int n_in,
                              void* d_out, int out_size, void* d_ws, size_t ws_size,
                              hipStream_t stream)
{
    (void)in_sizes; (void)n_in; (void)out_size; (void)ws_size;

    const float* x_in = (const float*)d_in[0];
    const float* fg   = (const float*)d_in[1];
    const float* fb   = (const float*)d_in[2];
    const float* wq   = (const float*)d_in[3];
    const float* bq   = (const float*)d_in[4];
    const float* wkv  = (const float*)d_in[5];
    const float* bkv  = (const float*)d_in[6];
    const float* wo   = (const float*)d_in[7];
    const float* bo   = (const float*)d_in[8];
    const float* w1   = (const float*)d_in[9];
    const float* b1   = (const float*)d_in[10];
    const float* w2   = (const float*)d_in[11];
    const float* b2   = (const float*)d_in[12];
    const float* attg = (const float*)d_in[13];
    const float* attb = (const float*)d_in[14];
    const float* ffng = (const float*)d_in[15];
    const float* ffnb = (const float*)d_in[16];

    float* x = (float*)d_out;                       // residual stream (fp32)

    char* wp = (char*)d_ws;
    float*          qkvbuf = (float*)wp;          wp += (size_t)MROWS*QSTR*4;   // 48 MB
    unsigned short* h1buf  = (unsigned short*)wp; wp += (size_t)MROWS*FFDIM*2;  // 32 MB
    unsigned short* hbuf   = (unsigned short*)wp; wp += (size_t)MROWS*DM*2;     //  8 MB
    unsigned short* attbuf = (unsigned short*)wp; wp += (size_t)MROWS*DM*2;     //  8 MB
    unsigned short* wt_qkv = (unsigned short*)wp; wp += (size_t)QSTR*DM*2;      //  6 MB
    unsigned short* wt_o   = (unsigned short*)wp; wp += (size_t)DM*DM*2;        //  2 MB
    unsigned short* wt_1   = (unsigned short*)wp; wp += (size_t)FFDIM*DM*2;     //  8 MB
    unsigned short* wt_2   = (unsigned short*)wp; wp += (size_t)DM*FFDIM*2;     //  8 MB
    float*          qkv_b  = (float*)wp;          wp += (size_t)NLAYER*QSTR*4;  // 96 KB

    hipMemcpyAsync(x, x_in, (size_t)MROWS*DM*sizeof(float),
                   hipMemcpyDeviceToDevice, stream);
    bias_concat_kernel<<<NLAYER*QSTR/256, 256, 0, stream>>>(bq, bkv, qkv_b);

    const dim3 blk(256);
    const dim3 g_qkv(QSTR/128,  MROWS/128);   // (24,32)
    const dim3 g_sq (DM/128,    MROWS/128);   // (8,32)
    const dim3 g_ff (FFDIM/128, MROWS/128);   // (32,32)
    const dim3 g_at (SEQ/64, NHEAD, BATCH);   // (32,16,2)

    for (int i = 0; i < NLAYER; i++){
        const float* wq_i  = wq  + (size_t)i*DM*DM;
        const float* wkv_i = wkv + (size_t)i*DM*2*DM;
        const float* wo_i  = wo  + (size_t)i*DM*DM;
        const float* bo_i  = bo  + (size_t)i*DM;
        const float* w1_i  = w1  + (size_t)i*DM*FFDIM;
        const float* b1_i  = b1  + (size_t)i*FFDIM;
        const float* w2_i  = w2  + (size_t)i*FFDIM*DM;
        const float* b2_i  = b2  + (size_t)i*DM;

        // weight transpose-casts for this layer (fp32 [K,N] -> bf16 [N,K])
        tcast_kernel<<<dim3(DM/32,    DM/32),    blk, 0, stream>>>(wq_i,  wt_qkv,            DM,    DM);
        tcast_kernel<<<dim3(2*DM/32,  DM/32),    blk, 0, stream>>>(wkv_i, wt_qkv + DM*DM,    DM,    2*DM);
        tcast_kernel<<<dim3(DM/32,    DM/32),    blk, 0, stream>>>(wo_i,  wt_o,              DM,    DM);
        tcast_kernel<<<dim3(FFDIM/32, DM/32),    blk, 0, stream>>>(w1_i,  wt_1,              DM,    FFDIM);
        tcast_kernel<<<dim3(DM/32,    FFDIM/32), blk, 0, stream>>>(w2_i,  wt_2,              FFDIM, DM);

        // h = LN(x) -> bf16
        ln_kernel<true><<<MROWS, blk, 0, stream>>>(x, attg + (size_t)i*DM, attb + (size_t)i*DM, hbuf);
        // qkv = h @ [wq|wkv] + [bq|bkv]   (fp32 out, feeds fp32 attention)
        gemm_bf16_kernel<false,false,false><<<g_qkv, blk, 0, stream>>>(
            hbuf, wt_qkv, qkv_b + (size_t)i*QSTR, nullptr, qkvbuf, QSTR, DM);
        // att = flash_attention(qkv) -> bf16
        attn_kernel<<<g_at, blk, 0, stream>>>(qkvbuf, attbuf);
        // x = x + att @ wo + bo
        gemm_bf16_kernel<false,true,false><<<g_sq, blk, 0, stream>>>(
            attbuf, wt_o, bo_i, x, x, DM, DM);
        // h = LN(x) -> bf16
        ln_kernel<true><<<MROWS, blk, 0, stream>>>(x, ffng + (size_t)i*DM, ffnb + (size_t)i*DM, hbuf);
        // h1 = softplus(h @ w1 + b1) -> bf16
        gemm_bf16_kernel<true,false,true><<<g_ff, blk, 0, stream>>>(
            hbuf, wt_1, b1_i, nullptr, h1buf, FFDIM, DM);
        // x = x + h1 @ w2 + b2
        gemm_bf16_kernel<false,true,false><<<g_sq, blk, 0, stream>>>(
            h1buf, wt_2, b2_i, x, x, DM, FFDIM);
    }
    // out = LN(x) fp32, in-place on d_out
    ln_kernel<false><<<MROWS, blk, 0, stream>>>(x, fg, fb, x);
}

// Round 3
// 3460.669 us; speedup vs baseline: 11.2795x; 11.2795x over previous
//
#include <hip/hip_runtime.h>
#include <math.h>

// Problem constants (fixed by the reference)
#define DM 1024
#define SEQ 2048
#define BATCH 2
#define NHEAD 16
#define HDIM 64
#define NLAYER 8
#define FFDIM 4096
#define MROWS (BATCH*SEQ)    // 4096
#define QSTR 3072            // fused qkv row stride (shorts)

typedef __attribute__((ext_vector_type(8))) unsigned short short8;
typedef __attribute__((ext_vector_type(8))) __bf16 bf16x8;
typedef __attribute__((ext_vector_type(4))) float f32x4;

__device__ __forceinline__ float softplus_f(float x){
    return fmaxf(x, 0.0f) + log1pf(__expf(-fabsf(x)));
}

// fp32 -> bf16 round-to-nearest-even (finite inputs)
__device__ __forceinline__ unsigned short f2bf(float f){
    unsigned u = __builtin_bit_cast(unsigned, f);
    u += 0x7fffu + ((u >> 16) & 1u);
    return (unsigned short)(u >> 16);
}

// async global->LDS, 16B per lane; LDS dest = wave-uniform base + lane*16
__device__ __forceinline__ void gload_lds16(const void* g, void* l){
    __builtin_amdgcn_global_load_lds(
        (const __attribute__((address_space(1))) unsigned int*)g,
        (__attribute__((address_space(3))) unsigned int*)l, 16, 0, 0);
}

// ---------------------------------------------------------------------------
// Transpose-cast: src fp32 [K,N] row-major -> dst bf16 [N,K] row-major.
__global__ __launch_bounds__(256) void tcast_kernel(
    const float* __restrict__ src, unsigned short* __restrict__ dst, int K, int N)
{
    __shared__ float tile[32][33];
    const int bn = blockIdx.x * 32, bk = blockIdx.y * 32;
    const int tx = threadIdx.x & 31, ty = threadIdx.x >> 5;
    #pragma unroll
    for (int i = 0; i < 32; i += 8)
        tile[ty + i][tx] = src[(size_t)(bk + ty + i) * N + bn + tx];
    __syncthreads();
    #pragma unroll
    for (int i = 0; i < 32; i += 8)
        dst[(size_t)(bn + ty + i) * K + bk + tx] = f2bf(tile[tx][ty + i]);
}

// concat [bq | bkv] per layer into [NLAYER][3072] fp32
__global__ __launch_bounds__(256) void bias_concat_kernel(
    const float* __restrict__ bq, const float* __restrict__ bkv, float* __restrict__ dst)
{
    const int i = blockIdx.x * 256 + threadIdx.x;
    const int l = i / QSTR, c = i % QSTR;
    dst[i] = (c < DM) ? bq[l * DM + c] : bkv[l * 2 * DM + (c - DM)];
}

// ---------------------------------------------------------------------------
// LayerNorm: one block per row of 1024 floats. eps=1e-3. Output fp32 or bf16.
template<bool OUT_BF16>
__global__ __launch_bounds__(256) void ln_kernel(
    const float* __restrict__ x, const float* __restrict__ gamma,
    const float* __restrict__ beta, void* __restrict__ outv)
{
    const int row = blockIdx.x;
    const int t = threadIdx.x;
    const float4 v = ((const float4*)(x + (size_t)row * DM))[t];
    float s  = v.x + v.y + v.z + v.w;
    float s2 = v.x*v.x + v.y*v.y + v.z*v.z + v.w*v.w;
    #pragma unroll
    for (int off = 32; off > 0; off >>= 1){
        s  += __shfl_down(s,  off);
        s2 += __shfl_down(s2, off);
    }
    __shared__ float red[8];
    const int wid = t >> 6;
    if ((t & 63) == 0){ red[wid] = s; red[4 + wid] = s2; }
    __syncthreads();
    if (t == 0){
        red[0] = red[0] + red[1] + red[2] + red[3];
        red[4] = red[4] + red[5] + red[6] + red[7];
    }
    __syncthreads();
    const float mean = red[0] * (1.0f / DM);
    const float var  = red[4] * (1.0f / DM) - mean * mean;
    const float rstd = rsqrtf(var + 1e-3f);
    const float4 g  = ((const float4*)gamma)[t];
    const float4 bt = ((const float4*)beta)[t];
    float ox = (v.x - mean) * rstd * g.x + bt.x;
    float oy = (v.y - mean) * rstd * g.y + bt.y;
    float oz = (v.z - mean) * rstd * g.z + bt.z;
    float ow = (v.w - mean) * rstd * g.w + bt.w;
    if (OUT_BF16){
        ushort4 o = make_ushort4(f2bf(ox), f2bf(oy), f2bf(oz), f2bf(ow));
        *(ushort4*)((unsigned short*)outv + (size_t)row * DM + t*4) = o;
    } else {
        ((float4*)((float*)outv + (size_t)row * DM))[t] = make_float4(ox, oy, oz, ow);
    }
}

// ---------------------------------------------------------------------------
// bf16 MFMA GEMM (m97 structure): C[M,N] = A[M,K] @ Bt[N,K]^T + bias.
template<bool SOFTPLUS, bool RESIDUAL, bool OUT_BF16>
__global__ __launch_bounds__(256) void gemm_bf16_kernel(
    const unsigned short* __restrict__ A, const unsigned short* __restrict__ Bt,
    const float* __restrict__ bias, const float* __restrict__ resid,
    void* __restrict__ Cv, int N, int K)
{
    __shared__ __align__(16) unsigned short As[128 * 32];
    __shared__ __align__(16) unsigned short Bs[128 * 32];
    const int t = threadIdx.x;
    const int lane = t & 63, w = t >> 6;
    const int bm = blockIdx.y * 128, bn = blockIdx.x * 128;

    const int srow = lane >> 2;
    const int scol = (lane & 3) * 8;
    const unsigned short* a_g0 = A  + (size_t)(bm + w*32 + srow) * K + scol;
    const unsigned short* a_g1 = a_g0 + (size_t)16 * K;
    const unsigned short* b_g0 = Bt + (size_t)(bn + w*32 + srow) * K + scol;
    const unsigned short* b_g1 = b_g0 + (size_t)16 * K;
    unsigned short* a_l0 = &As[(w*32     ) * 32];
    unsigned short* a_l1 = &As[(w*32 + 16) * 32];
    unsigned short* b_l0 = &Bs[(w*32     ) * 32];
    unsigned short* b_l1 = &Bs[(w*32 + 16) * 32];

    const int wr = (w >> 1) * 64;
    const int wc = (w & 1) * 64;
    const int fm = lane & 15;
    const int fq = (lane >> 4) * 8;

    f32x4 acc[4][4] = {};

    for (int k0 = 0; k0 < K; k0 += 32){
        __syncthreads();
        gload_lds16(a_g0 + k0, a_l0);
        gload_lds16(a_g1 + k0, a_l1);
        gload_lds16(b_g0 + k0, b_l0);
        gload_lds16(b_g1 + k0, b_l1);
        __syncthreads();

        bf16x8 af[4], bfr[4];
        #pragma unroll
        for (int mi = 0; mi < 4; mi++)
            af[mi] = __builtin_bit_cast(bf16x8,
                *(const short8*)&As[(wr + mi*16 + fm) * 32 + fq]);
        #pragma unroll
        for (int ni = 0; ni < 4; ni++)
            bfr[ni] = __builtin_bit_cast(bf16x8,
                *(const short8*)&Bs[(wc + ni*16 + fm) * 32 + fq]);
        #pragma unroll
        for (int mi = 0; mi < 4; mi++)
            #pragma unroll
            for (int ni = 0; ni < 4; ni++)
                acc[mi][ni] = __builtin_amdgcn_mfma_f32_16x16x32_bf16(
                    af[mi], bfr[ni], acc[mi][ni], 0, 0, 0);
    }

    const int crow = (lane >> 4) * 4;
    const int ccol = lane & 15;
    #pragma unroll
    for (int mi = 0; mi < 4; mi++){
        #pragma unroll
        for (int r = 0; r < 4; r++){
            const size_t row = (size_t)bm + wr + mi*16 + crow + r;
            #pragma unroll
            for (int ni = 0; ni < 4; ni++){
                const int col = bn + wc + ni*16 + ccol;
                float v = acc[mi][ni][r] + bias[col];
                if (SOFTPLUS) v = softplus_f(v);
                if (RESIDUAL) v += resid[row * N + col];
                if (OUT_BF16) ((unsigned short*)Cv)[row * N + col] = f2bf(v);
                else          ((float*)Cv)[row * N + col] = v;
            }
        }
    }
}

// ---------------------------------------------------------------------------
// MFMA flash attention, ALiBi + causal. qkv bf16 [B*S, 3072]; out bf16.
// Per block: 64 q-rows; wave w owns q-slice w*16..w*16+15.
// S^T = K·Q^T  (A=K rows, B=Q rows -> no transposes; C-layout gives each
// lane 4 consecutive kpos for ONE q => scalar m/l per lane, b64 P-writes
// directly in the PV A-operand layout Ps[q][kpos]).
// V staged transposed Vt[d][kpos] via stride-coalesced ushort loads.
// All LDS rows padded to 72 shorts (stride 36 words -> 2-way alias, free).
__global__ __launch_bounds__(256, 4) void attn_kernel(
    const unsigned short* __restrict__ qkv, unsigned short* __restrict__ outg)
{
    __shared__ __align__(16) unsigned short Qs[64][72];
    __shared__ __align__(16) unsigned short Ks[64][72];
    __shared__ __align__(16) unsigned short Vt[64][72];
    __shared__ __align__(16) unsigned short Ps[64][72];

    const int b = blockIdx.z, h = blockIdx.y, qt = blockIdx.x;
    const int t = threadIdx.x;
    const int lane = t & 63, w = t >> 6;
    const int g = lane >> 4, s = lane & 15;   // quad, sub-lane

    const size_t qrow0 = (size_t)(b * SEQ + qt * 64);
    const int srow = t >> 2, slc = t & 3;     // row-staging map (4 lanes/row)

    // --- stage Q tile (once) ---
    {
        const unsigned short* src = qkv + (qrow0 + srow) * QSTR + h*HDIM + slc*16;
        *(uint4*)&Qs[srow][slc*16]     = *(const uint4*)(src);
        *(uint4*)&Qs[srow][slc*16 + 8] = *(const uint4*)(src + 8);
    }
    __syncthreads();
    // Q fragments are block-constant: hoist out of the K-loop
    bf16x8 qf0 = __builtin_bit_cast(bf16x8, *(const short8*)&Qs[w*16 + s][g*8]);
    bf16x8 qf1 = __builtin_bit_cast(bf16x8, *(const short8*)&Qs[w*16 + s][32 + g*8]);

    const float mh = exp2f(-0.5f * (float)(h + 1));   // ALiBi slope
    const int qi = qt*64 + w*16 + s;                  // this lane's q index
    float m_i = -1e30f, l_i = 0.0f;
    f32x4 accO[4] = {};

    for (int kt = 0; kt <= qt; kt++){
        __syncthreads();   // prior PV done reading Vt before restage
        const size_t krow0 = (size_t)(b * SEQ + kt * 64);
        // stage K rows [kpos][d]
        {
            const unsigned short* src = qkv + (krow0 + srow) * QSTR + DM + h*HDIM + slc*16;
            *(uint4*)&Ks[srow][slc*16]     = *(const uint4*)(src);
            *(uint4*)&Ks[srow][slc*16 + 8] = *(const uint4*)(src + 8);
        }
        // stage V transposed [d][kpos]: lane d=lane (coalesced 128B per kpos)
        {
            unsigned short tmp[16];
            #pragma unroll
            for (int j = 0; j < 16; j++)
                tmp[j] = qkv[(krow0 + w*16 + j) * QSTR + 2*DM + h*HDIM + lane];
            *(uint4*)&Vt[lane][w*16]     = *(const uint4*)&tmp[0];
            *(uint4*)&Vt[lane][w*16 + 8] = *(const uint4*)&tmp[8];
        }
        __syncthreads();

        // --- S^T = K·Q^T : 4 kpos-tiles (mi), contraction d=64 in 2 chunks ---
        f32x4 sacc[4] = {};
        #pragma unroll
        for (int mi = 0; mi < 4; mi++){
            bf16x8 kf0 = __builtin_bit_cast(bf16x8, *(const short8*)&Ks[mi*16 + s][g*8]);
            bf16x8 kf1 = __builtin_bit_cast(bf16x8, *(const short8*)&Ks[mi*16 + s][32 + g*8]);
            sacc[mi] = __builtin_amdgcn_mfma_f32_16x16x32_bf16(kf0, qf0, sacc[mi], 0, 0, 0);
            sacc[mi] = __builtin_amdgcn_mfma_f32_16x16x32_bf16(kf1, qf1, sacc[mi], 0, 0, 0);
        }

        // --- scale + ALiBi + causal; lane holds 16 kpos values for its q ---
        float sc[16];
        float mloc = -1e30f;
        #pragma unroll
        for (int mi = 0; mi < 4; mi++)
            #pragma unroll
            for (int r = 0; r < 4; r++){
                const int kj = kt*64 + mi*16 + g*4 + r;
                const float v = (kj <= qi)
                    ? fmaf(sacc[mi][r], 0.125f, mh * (float)(kj - qi)) : -1e30f;
                sc[mi*4 + r] = v;
                mloc = fmaxf(mloc, v);
            }
        // reduce over the 4 quads (lanes with same s): xor 16, 32
        mloc = fmaxf(mloc, __shfl_xor(mloc, 16));
        mloc = fmaxf(mloc, __shfl_xor(mloc, 32));
        const float nm = fmaxf(m_i, mloc);
        const float alpha = __expf(m_i - nm);
        m_i = nm;

        float rsum = 0.0f;
        #pragma unroll
        for (int mi = 0; mi < 4; mi++){
            const float p0 = __expf(sc[mi*4+0] - nm);
            const float p1 = __expf(sc[mi*4+1] - nm);
            const float p2 = __expf(sc[mi*4+2] - nm);
            const float p3 = __expf(sc[mi*4+3] - nm);
            rsum += (p0 + p1) + (p2 + p3);
            // P write: 4 consecutive kpos for this q -> single b64
            *(ushort4*)&Ps[w*16 + s][mi*16 + g*4] =
                make_ushort4(f2bf(p0), f2bf(p1), f2bf(p2), f2bf(p3));
        }
        rsum += __shfl_xor(rsum, 16);
        rsum += __shfl_xor(rsum, 32);
        l_i = l_i * alpha + rsum;

        // rescale accO: lane holds O rows g*4+r; alpha for row r' lives in lane r'
        float av[4];
        #pragma unroll
        for (int r = 0; r < 4; r++) av[r] = __shfl(alpha, g*4 + r);
        #pragma unroll
        for (int ni = 0; ni < 4; ni++)
            #pragma unroll
            for (int r = 0; r < 4; r++) accO[ni][r] *= av[r];

        // --- O += P·V : A=Ps rows (own q-slice, same-wave data), B=Vt rows ---
        bf16x8 pf0 = __builtin_bit_cast(bf16x8, *(const short8*)&Ps[w*16 + s][g*8]);
        bf16x8 pf1 = __builtin_bit_cast(bf16x8, *(const short8*)&Ps[w*16 + s][32 + g*8]);
        #pragma unroll
        for (int ni = 0; ni < 4; ni++){
            bf16x8 vf0 = __builtin_bit_cast(bf16x8, *(const short8*)&Vt[ni*16 + s][g*8]);
            bf16x8 vf1 = __builtin_bit_cast(bf16x8, *(const short8*)&Vt[ni*16 + s][32 + g*8]);
            accO[ni] = __builtin_amdgcn_mfma_f32_16x16x32_bf16(pf0, vf0, accO[ni], 0, 0, 0);
            accO[ni] = __builtin_amdgcn_mfma_f32_16x16x32_bf16(pf1, vf1, accO[ni], 0, 0, 0);
        }
    }

    // epilogue: per-row 1/l broadcast, write bf16
    float lv[4];
    #pragma unroll
    for (int r = 0; r < 4; r++) lv[r] = 1.0f / __shfl(l_i, g*4 + r);
    #pragma unroll
    for (int ni = 0; ni < 4; ni++)
        #pragma unroll
        for (int r = 0; r < 4; r++)
            outg[(qrow0 + w*16 + g*4 + r) * DM + h*HDIM + ni*16 + s] =
                f2bf(accO[ni][r] * lv[r]);
}

// ---------------------------------------------------------------------------
extern "C" void kernel_launch(void* const* d_in, const int* in_sizes, int n_in,
                              void* d_out, int out_size, void* d_ws, size_t ws_size,
                              hipStream_t stream)
{
    (void)in_sizes; (void)n_in; (void)out_size; (void)ws_size;

    const float* x_in = (const float*)d_in[0];
    const float* fg   = (const float*)d_in[1];
    const float* fb   = (const float*)d_in[2];
    const float* wq   = (const float*)d_in[3];
    const float* bq   = (const float*)d_in[4];
    const float* wkv  = (const float*)d_in[5];
    const float* bkv  = (const float*)d_in[6];
    const float* wo   = (const float*)d_in[7];
    const float* bo   = (const float*)d_in[8];
    const float* w1   = (const float*)d_in[9];
    const float* b1   = (const float*)d_in[10];
    const float* w2   = (const float*)d_in[11];
    const float* b2   = (const float*)d_in[12];
    const float* attg = (const float*)d_in[13];
    const float* attb = (const float*)d_in[14];
    const float* ffng = (const float*)d_in[15];
    const float* ffnb = (const float*)d_in[16];

    float* x = (float*)d_out;                       // residual stream (fp32)

    char* wp = (char*)d_ws;
    unsigned short* qkvbuf = (unsigned short*)wp; wp += (size_t)MROWS*QSTR*2;   // 24 MB
    unsigned short* h1buf  = (unsigned short*)wp; wp += (size_t)MROWS*FFDIM*2;  // 32 MB
    unsigned short* hbuf   = (unsigned short*)wp; wp += (size_t)MROWS*DM*2;     //  8 MB
    unsigned short* attbuf = (unsigned short*)wp; wp += (size_t)MROWS*DM*2;     //  8 MB
    unsigned short* wt_qkv = (unsigned short*)wp; wp += (size_t)QSTR*DM*2;      //  6 MB
    unsigned short* wt_o   = (unsigned short*)wp; wp += (size_t)DM*DM*2;        //  2 MB
    unsigned short* wt_1   = (unsigned short*)wp; wp += (size_t)FFDIM*DM*2;     //  8 MB
    unsigned short* wt_2   = (unsigned short*)wp; wp += (size_t)DM*FFDIM*2;     //  8 MB
    float*          qkv_b  = (float*)wp;          wp += (size_t)NLAYER*QSTR*4;  // 96 KB

    hipMemcpyAsync(x, x_in, (size_t)MROWS*DM*sizeof(float),
                   hipMemcpyDeviceToDevice, stream);
    bias_concat_kernel<<<NLAYER*QSTR/256, 256, 0, stream>>>(bq, bkv, qkv_b);

    const dim3 blk(256);
    const dim3 g_qkv(QSTR/128,  MROWS/128);   // (24,32)
    const dim3 g_sq (DM/128,    MROWS/128);   // (8,32)
    const dim3 g_ff (FFDIM/128, MROWS/128);   // (32,32)
    const dim3 g_at (SEQ/64, NHEAD, BATCH);   // (32,16,2)

    for (int i = 0; i < NLAYER; i++){
        const float* wq_i  = wq  + (size_t)i*DM*DM;
        const float* wkv_i = wkv + (size_t)i*DM*2*DM;
        const float* wo_i  = wo  + (size_t)i*DM*DM;
        const float* bo_i  = bo  + (size_t)i*DM;
        const float* w1_i  = w1  + (size_t)i*DM*FFDIM;
        const float* b1_i  = b1  + (size_t)i*FFDIM;
        const float* w2_i  = w2  + (size_t)i*FFDIM*DM;
        const float* b2_i  = b2  + (size_t)i*DM;

        tcast_kernel<<<dim3(DM/32,    DM/32),    blk, 0, stream>>>(wq_i,  wt_qkv,         DM,    DM);
        tcast_kernel<<<dim3(2*DM/32,  DM/32),    blk, 0, stream>>>(wkv_i, wt_qkv + DM*DM, DM,    2*DM);
        tcast_kernel<<<dim3(DM/32,    DM/32),    blk, 0, stream>>>(wo_i,  wt_o,           DM,    DM);
        tcast_kernel<<<dim3(FFDIM/32, DM/32),    blk, 0, stream>>>(w1_i,  wt_1,           DM,    FFDIM);
        tcast_kernel<<<dim3(DM/32,    FFDIM/32), blk, 0, stream>>>(w2_i,  wt_2,           FFDIM, DM);

        // h = LN(x) -> bf16
        ln_kernel<true><<<MROWS, blk, 0, stream>>>(x, attg + (size_t)i*DM, attb + (size_t)i*DM, hbuf);
        // qkv = h @ [wq|wkv] + [bq|bkv] -> bf16
        gemm_bf16_kernel<false,false,true><<<g_qkv, blk, 0, stream>>>(
            hbuf, wt_qkv, qkv_b + (size_t)i*QSTR, nullptr, qkvbuf, QSTR, DM);
        // att = flash_attention(qkv) -> bf16
        attn_kernel<<<g_at, blk, 0, stream>>>(qkvbuf, attbuf);
        // x = x + att @ wo + bo
        gemm_bf16_kernel<false,true,false><<<g_sq, blk, 0, stream>>>(
            attbuf, wt_o, bo_i, x, x, DM, DM);
        // h = LN(x) -> bf16
        ln_kernel<true><<<MROWS, blk, 0, stream>>>(x, ffng + (size_t)i*DM, ffnb + (size_t)i*DM, hbuf);
        // h1 = softplus(h @ w1 + b1) -> bf16
        gemm_bf16_kernel<true,false,true><<<g_ff, blk, 0, stream>>>(
            hbuf, wt_1, b1_i, nullptr, h1buf, FFDIM, DM);
        // x = x + h1 @ w2 + b2
        gemm_bf16_kernel<false,true,false><<<g_sq, blk, 0, stream>>>(
            h1buf, wt_2, b2_i, x, x, DM, FFDIM);
    }
    // out = LN(x) fp32, in-place on d_out
    ln_kernel<false><<<MROWS, blk, 0, stream>>>(x, fg, fb, x);
}